// Round 27
// baseline (92.378 us; speedup 1.0000x reference)
//
#include <hip/hip_runtime.h>
#include <math.h>
#include <stdint.h>

#define NCLS 128
#define TPB  256
#define MAXBLK 1024
constexpr float ALPHA = 0.5f;
constexpr float BETA_ = 0.5f;
constexpr float EPS_ = 1e-9f;

// ws: gLbf[1024][128] float (512KB) | gcntw[1024][128] u16 (256KB) | gcef[1024] float (4KB)
// = 772 KB total (<= ~1MB proven usable by R13 probe). Atomic-free coalesced
// write-flush; every slot written every launch -> no zeroing kernel.

// THREAD-OWNS-ROW, direct global loads, zero cross-lane ops in the hot loop.
// Each thread: 32 float4 loads (A/B prefetch groups of 8), 128 exp into 4
// accumulators, one 4B gather for the target logit, fully lane-parallel epilogue.
// ~4.3 wave-ops/row vs ~17.5 for the butterfly structure (R22/R26 champion).
__global__ __launch_bounds__(TPB, 4) void loss_main(
    const float* __restrict__ y_pred,
    const int*   __restrict__ y_true,
    float* __restrict__ gLbf, uint16_t* __restrict__ gcntw,
    float* __restrict__ gcef, int nrows, int nblocks)
{
    __shared__ float    sL[NCLS];
    __shared__ unsigned scnt[NCLS];
    __shared__ float    sce;

    const int t = threadIdx.x;
    if (t == 0) sce = 0.f;
    if (t < NCLS) { sL[t] = 0.f; scnt[t] = 0u; }
    __syncthreads();

    float ce_local = 0.f;
    const int stride = nblocks * TPB;

    for (int row = blockIdx.x * TPB + t; row < nrows; row += stride) {
        const float4* rp  = reinterpret_cast<const float4*>(y_pred + (size_t)row * NCLS);
        const int     lab = y_true[row];

        float4 va[8], vb[8];
        float S0 = 0.f, S1 = 0.f, S2 = 0.f, S3 = 0.f, e0 = 0.f;

        #pragma unroll
        for (int i = 0; i < 8; ++i) va[i] = rp[i];
        #pragma unroll
        for (int i = 0; i < 8; ++i) vb[i] = rp[8 + i];
        // target logit: single gather; its line is being fetched by the row loads
        const float tv = y_pred[(size_t)row * NCLS + lab];

        #pragma unroll
        for (int i = 0; i < 8; ++i) {                 // chunks 0..7
            const float4 c = va[i];
            const float ex = __expf(c.x);
            if (i == 0) e0 = ex;                      // compile-time select
            S0 += ex; S1 += __expf(c.y); S2 += __expf(c.z); S3 += __expf(c.w);
        }
        #pragma unroll
        for (int i = 0; i < 8; ++i) va[i] = rp[16 + i];
        #pragma unroll
        for (int i = 0; i < 8; ++i) {                 // chunks 8..15
            const float4 c = vb[i];
            S0 += __expf(c.x); S1 += __expf(c.y); S2 += __expf(c.z); S3 += __expf(c.w);
        }
        #pragma unroll
        for (int i = 0; i < 8; ++i) vb[i] = rp[24 + i];
        #pragma unroll
        for (int i = 0; i < 8; ++i) {                 // chunks 16..23
            const float4 c = va[i];
            S0 += __expf(c.x); S1 += __expf(c.y); S2 += __expf(c.z); S3 += __expf(c.w);
        }
        #pragma unroll
        for (int i = 0; i < 8; ++i) {                 // chunks 24..31
            const float4 c = vb[i];
            S0 += __expf(c.x); S1 += __expf(c.y); S2 += __expf(c.z); S3 += __expf(c.w);
        }

        const float S    = (S0 + S1) + (S2 + S3);
        const float logS = __logf(S);
        ce_local += tv - logS;
        const float d  = (lab == 0) ? e0 : (S - e0);
        const float c0 = __logf(__fmaf_rn(EPS_, S, d)) - logS;
        atomicAdd(&sL[lab], (lab == 0) ? ALPHA * c0 : c0);
        atomicAdd(&scnt[lab], 1u);
    }

    // ce: wave butterfly, one LDS atomic per wave
    #pragma unroll
    for (int off = 32; off; off >>= 1) ce_local += __shfl_xor(ce_local, off);
    if ((t & 63) == 0) atomicAdd(&sce, ce_local);
    __syncthreads();

    // coalesced write-flush: block owns row blockIdx.x of [blk][cls] arrays
    if (t < NCLS) {
        gLbf[(size_t)blockIdx.x * NCLS + t]  = sL[t];
        gcntw[(size_t)blockIdx.x * NCLS + t] = (uint16_t)scnt[t];
    }
    if (t == 0) gcef[blockIdx.x] = sce;
}

// Parallel finalize: 1024 threads, 8 groups; group g sums its share of block
// slots per class (coalesced: fixed slot, consecutive classes), LDS tree + waves.
__global__ __launch_bounds__(1024) void loss_final(
    const float* __restrict__ gLbf,          // [nblocks][128]
    const uint16_t* __restrict__ gcntw,      // [nblocks][128]
    const float* __restrict__ gcef,          // [nblocks]
    float* __restrict__ out, int nrows, int nblocks)
{
    __shared__ double sLc[8][NCLS];
    __shared__ double snc[8][NCLS];
    __shared__ double sred[4];

    const int t = threadIdx.x;
    const int c = t & (NCLS - 1);
    const int g = t >> 7;                    // 0..7
    const int per = (nblocks + 7) >> 3;

    double Lc = 0.0, nc = 0.0;
    const int bend = min((g + 1) * per, nblocks);
    for (int b = g * per; b < bend; ++b) {
        Lc += (double)gLbf[(size_t)b * NCLS + c];
        nc += (double)gcntw[(size_t)b * NCLS + c];
    }
    sLc[g][c] = Lc; snc[g][c] = nc;
    __syncthreads();

    if (t < NCLS) {
        double L = 0.0, n = 0.0;
        #pragma unroll
        for (int gg = 0; gg < 8; ++gg) { L += sLc[gg][t]; n += snc[gg][t]; }
        sLc[0][t] = L; snc[0][t] = n;
    }
    __syncthreads();

    const double denom = (double)nrows - snc[0][0];
    double local = 0.0;
    if (t < NCLS) {
        const double L = sLc[0][t], n = snc[0][t];
        local = (t == 0) ? L : (double)BETA_ * (1.0 - n / denom) * L;
    }
    #pragma unroll
    for (int off = 32; off; off >>= 1) local += __shfl_xor(local, off);
    if (t < NCLS && (t & 63) == 0) sred[t >> 6] = local;   // sred[0], sred[1]

    if (t >= 128 && t < 192) {               // one wave sums gcef[nblocks]
        const int l = t - 128;
        double cep = 0.0;
        for (int b = l; b < nblocks; b += 64) cep += (double)gcef[b];
        #pragma unroll
        for (int off = 32; off; off >>= 1) cep += __shfl_xor(cep, off);
        if (l == 0) sred[2] = cep;
    }
    __syncthreads();

    if (t == 0) {
        const double ce = -sred[2] / (double)nrows;
        out[0] = (float)(ce - (sred[0] + sred[1]) / (double)nrows);
    }
}

extern "C" void kernel_launch(void* const* d_in, const int* in_sizes, int n_in,
                              void* d_out, int out_size, void* d_ws, size_t ws_size,
                              hipStream_t stream) {
    const float* y_pred = (const float*)d_in[0];
    const int*   y_true = (const int*)d_in[1];
    const int nrows = in_sizes[1];

    float*    gLbf  = (float*)d_ws;                           // 524288 B
    uint16_t* gcntw = (uint16_t*)((char*)d_ws + 524288);      // 262144 B
    float*    gcef  = (float*)((char*)d_ws + 786432);         // 4096 B

    int nblocks = (nrows + TPB - 1) / TPB;
    if (nblocks > MAXBLK) nblocks = MAXBLK;

    loss_main<<<dim3(nblocks), dim3(TPB), 0, stream>>>(
        y_pred, y_true, gLbf, gcntw, gcef, nrows, nblocks);
    loss_final<<<dim3(1), dim3(1024), 0, stream>>>(
        gLbf, gcntw, gcef, (float*)d_out, nrows, nblocks);
}

// Round 28
// 37.879 us; speedup vs baseline: 2.4388x; 2.4388x over previous
//
#include <hip/hip_runtime.h>
#include <math.h>
#include <stdint.h>

#define NCLS 128
#define NBLK 256
constexpr float ALPHA = 0.5f;
constexpr float BETA_ = 0.5f;
constexpr float EPS_ = 1e-9f;

// ws: gLb[256][128] double (262144 B) | gceb[256] double (2048 B) | gcntb[256][128] uint (131072 B)
// Atomic-free flush, transposed [blk][cls] layout (one coalesced 1KB burst per
// block); every slot written every launch -> no zeroing kernel.

// R26 champion + WAVE STAGGER: each wave sleeps (w&7)*~64..448 cyc once at start.
// The hot loop is barrier-free with identical-length iterations, so the initial
// offset persists: waves de-phase, one wave's LOAD burst flies under its
// siblings' compute. Attacks the phase-locked convoy (R17: VALU 48% + HBM 26%,
// BOTH idle -> waves stall on vmcnt(0) together, compute together).
__global__ __launch_bounds__(1024, 4) void loss_main(
    const float* __restrict__ y_pred,
    const int*   __restrict__ y_true,
    double* __restrict__ gLb, unsigned int* __restrict__ gcntb,
    double* __restrict__ gceb, int nrows)
{
    __shared__ float    sL[NCLS];
    __shared__ unsigned scnt[NCLS];
    __shared__ float    sce;

    const int t = threadIdx.x;
    if (t == 0) sce = 0.f;
    if (t < NCLS) { sL[t] = 0.f; scnt[t] = 0u; }
    __syncthreads();

    const int lane = t & 63;
    const int half = lane >> 5;
    const int l32  = lane & 31;
    const int w    = t >> 6;                                      // wave in block
    const int wgl  = blockIdx.x * (blockDim.x >> 6) + w;          // 0..4095
    const int nW   = gridDim.x * (blockDim.x >> 6);               // 4096
    const int nPairs = nrows >> 1;

    // ---- temporal de-phasing: stagger waves so LOAD bursts rotate across the CU
    switch (w & 7) {                       // s_sleep arg must be an immediate
        case 1: __builtin_amdgcn_s_sleep(1); break;
        case 2: __builtin_amdgcn_s_sleep(2); break;
        case 3: __builtin_amdgcn_s_sleep(3); break;
        case 4: __builtin_amdgcn_s_sleep(4); break;
        case 5: __builtin_amdgcn_s_sleep(5); break;
        case 6: __builtin_amdgcn_s_sleep(6); break;
        case 7: __builtin_amdgcn_s_sleep(7); break;
        default: break;
    }

    float ce_local = 0.f;

    int p0 = wgl * 8;
    for (; p0 + 7 < nPairs; p0 += nW * 8) {
        // ---- LOAD phase: 8x float4 (1KB/wave each) + 8 labels, all issued first
        float4 v[8]; int lab[8];
        const float* base = y_pred + ((size_t)(p0 << 1) + half) * NCLS + (l32 << 2);
        #pragma unroll
        for (int u = 0; u < 8; ++u) {
            v[u]   = *reinterpret_cast<const float4*>(base + (size_t)(u << 1) * NCLS);
            lab[u] = y_true[((p0 + u) << 1) + half];
        }
        __builtin_amdgcn_sched_barrier(0);   // pin: no compute issued before loads

        // ---- EXP phase: v dies here (S, e0, owner-lane tv fold)
        float S[8], e0[8];
        #pragma unroll
        for (int u = 0; u < 8; ++u) {
            const float ex = __expf(v[u].x), ey = __expf(v[u].y);
            const float ez = __expf(v[u].z), ew = __expf(v[u].w);
            e0[u] = ex;                      // valid on lane 0/32 (col 0) only
            S[u]  = (ex + ey) + (ez + ew);
            if ((lab[u] >> 2) == l32) {      // owner lane folds target logit now
                const int ls = lab[u] & 3;
                ce_local += (ls == 0) ? v[u].x : (ls == 1) ? v[u].y
                          : (ls == 2) ? v[u].z : v[u].w;
            }
        }
        // ---- 8 interleaved 5-step butterflies (S lands on all lanes)
        #pragma unroll
        for (int off = 16; off; off >>= 1) {
            #pragma unroll
            for (int u = 0; u < 8; ++u) S[u] += __shfl_xor(S[u], off);
        }
        // ---- distribute: lane l32==u owns row-pair u of its half
        float e0m = 1.f, Sm = 1.f; int labm = 0;
        #pragma unroll
        for (int u = 0; u < 8; ++u) {
            const float b = __shfl(e0[u], half << 5);   // bcast col-0 exp from lane 0/32
            if (l32 == u) { e0m = b; Sm = S[u]; labm = lab[u]; }
        }
        // ---- wave-parallel epilogue: 16 lanes (8 per half) at once
        if (l32 < 8) {
            const float logS = __logf(Sm);
            ce_local -= logS;
            const float d = (labm == 0) ? e0m : (Sm - e0m);
            const float c0 = __logf(__fmaf_rn(EPS_, Sm, d)) - logS;
            const float contrib = (labm == 0) ? ALPHA * c0 : c0;
            atomicAdd(&sL[labm], contrib);
            atomicAdd(&scnt[labm], 1u);
        }
    }
    // tail: leftover single pairs (empty at 262144 rows; kept for generality)
    for (; p0 < nPairs; ++p0) {
        const int row = (p0 << 1) + half;
        const float4 v = *reinterpret_cast<const float4*>(
            y_pred + (size_t)row * NCLS + (l32 << 2));
        const int lab = y_true[row];
        const float ex = __expf(v.x), ey = __expf(v.y);
        const float ez = __expf(v.z), ew = __expf(v.w);
        float S = (ex + ey) + (ez + ew);
        if ((lab >> 2) == l32) {
            const int ls = lab & 3;
            ce_local += (ls == 0) ? v.x : (ls == 1) ? v.y : (ls == 2) ? v.z : v.w;
        }
        #pragma unroll
        for (int off = 16; off; off >>= 1) S += __shfl_xor(S, off);
        if (l32 == 0) {
            const float logS = __logf(S);
            ce_local -= logS;
            const float d = (lab == 0) ? ex : (S - ex);
            const float c0 = __logf(__fmaf_rn(EPS_, S, d)) - logS;
            const float contrib = (lab == 0) ? ALPHA * c0 : c0;
            atomicAdd(&sL[lab], contrib);
            atomicAdd(&scnt[lab], 1u);
        }
    }
    if ((nrows & 1) && wgl == 0) {
        const int row = nrows - 1;
        const float4 v = *reinterpret_cast<const float4*>(
            y_pred + (size_t)row * NCLS + (l32 << 2));
        const int lab = y_true[row];
        if (half == 0) {
            const float ex = __expf(v.x), ey = __expf(v.y);
            const float ez = __expf(v.z), ew = __expf(v.w);
            float S = (ex + ey) + (ez + ew);
            if ((lab >> 2) == l32) {
                const int ls = lab & 3;
                ce_local += (ls == 0) ? v.x : (ls == 1) ? v.y : (ls == 2) ? v.z : v.w;
            }
            #pragma unroll
            for (int off = 16; off; off >>= 1) S += __shfl_xor(S, off);
            if (l32 == 0) {
                const float logS = __logf(S);
                ce_local -= logS;
                const float d = (lab == 0) ? ex : (S - ex);
                const float c0 = __logf(__fmaf_rn(EPS_, S, d)) - logS;
                const float contrib = (lab == 0) ? ALPHA * c0 : c0;
                atomicAdd(&sL[lab], contrib);
                atomicAdd(&scnt[lab], 1u);
            }
        }
    }

    float lp = ce_local;
    #pragma unroll
    for (int off = 32; off; off >>= 1) lp += __shfl_xor(lp, off);
    if (lane == 0) atomicAdd(&sce, lp);
    __syncthreads();

    // coalesced write-flush: block owns row blockIdx.x of [blk][cls] arrays.
    if (t < NCLS) {
        gLb[(size_t)blockIdx.x * NCLS + t]   = (double)sL[t];
        gcntb[(size_t)blockIdx.x * NCLS + t] = scnt[t];
    }
    if (t == 0) gceb[blockIdx.x] = (double)sce;
}

// Parallel finalize: 1024 threads. 8 threads per class x 32 slots, coalesced
// (for fixed slot b, lanes read consecutive classes). LDS tree + wave butterflies.
__global__ __launch_bounds__(1024) void loss_final(
    const double* __restrict__ gLb,          // [256][128]
    const unsigned int* __restrict__ gcntb,  // [256][128]
    const double* __restrict__ gceb,         // [256]
    float* __restrict__ out, int nrows)
{
    __shared__ double sLc[8][NCLS];
    __shared__ double snc[8][NCLS];
    __shared__ double sred[4];

    const int t = threadIdx.x;
    const int c = t & (NCLS - 1);
    const int g = t >> 7;                    // 0..7

    double Lc = 0.0, nc = 0.0;
    for (int b = g * 32; b < g * 32 + 32; ++b) {
        Lc += gLb[(size_t)b * NCLS + c];
        nc += (double)gcntb[(size_t)b * NCLS + c];
    }
    sLc[g][c] = Lc; snc[g][c] = nc;
    __syncthreads();

    if (t < NCLS) {
        double L = 0.0, n = 0.0;
        #pragma unroll
        for (int gg = 0; gg < 8; ++gg) { L += sLc[gg][t]; n += snc[gg][t]; }
        sLc[0][t] = L; snc[0][t] = n;
    }
    __syncthreads();

    const double denom = (double)nrows - snc[0][0];
    double local = 0.0;
    if (t < NCLS) {
        const double L = sLc[0][t], n = snc[0][t];
        local = (t == 0) ? L : (double)BETA_ * (1.0 - n / denom) * L;
    }
    #pragma unroll
    for (int off = 32; off; off >>= 1) local += __shfl_xor(local, off);
    if (t < NCLS && (t & 63) == 0) sred[t >> 6] = local;   // sred[0], sred[1]

    if (t >= 128 && t < 192) {               // one wave sums gceb[256]
        const int l = t - 128;
        double cep = gceb[l] + gceb[l + 64] + gceb[l + 128] + gceb[l + 192];
        #pragma unroll
        for (int off = 32; off; off >>= 1) cep += __shfl_xor(cep, off);
        if (l == 0) sred[2] = cep;
    }
    __syncthreads();

    if (t == 0) {
        const double ce = -sred[2] / (double)nrows;
        out[0] = (float)(ce - (sred[0] + sred[1]) / (double)nrows);
    }
}

extern "C" void kernel_launch(void* const* d_in, const int* in_sizes, int n_in,
                              void* d_out, int out_size, void* d_ws, size_t ws_size,
                              hipStream_t stream) {
    const float* y_pred = (const float*)d_in[0];
    const int*   y_true = (const int*)d_in[1];
    const int nrows = in_sizes[1];

    double*   gLb   = (double*)d_ws;                          // 262144 B
    double*   gceb  = (double*)((char*)d_ws + 262144);        // 2048 B
    unsigned* gcntb = (unsigned*)((char*)d_ws + 264192);      // 131072 B

    loss_main<<<dim3(NBLK), dim3(1024), 0, stream>>>(y_pred, y_true, gLb, gcntb, gceb, nrows);
    loss_final<<<dim3(1), dim3(1024), 0, stream>>>(gLb, gcntb, gceb, (float*)d_out, nrows);
}

// Round 29
// 37.082 us; speedup vs baseline: 2.4912x; 1.0215x over previous
//
#include <hip/hip_runtime.h>
#include <math.h>
#include <stdint.h>

#define NCLS 128
#define NBLK 256
constexpr float ALPHA = 0.5f;
constexpr float BETA_ = 0.5f;
constexpr float EPS_ = 1e-9f;

// ws: gLb[256][128] double (262144 B) | gceb[256] double (2048 B) | gcntb[256][128] uint (131072 B)
// Atomic-free flush, transposed [blk][cls] layout; every slot written every
// launch -> no zeroing kernel.

// R26 champion + ROTATED SOFTWARE PIPELINE: batch n+1's loads are issued right
// after EXP(n) (v[] is dead there), pinned by sched_barrier(0) so they cannot
// sink below the butterfly/epilogue. Each wave thus keeps ~8KB in flight during
// its ~1500cyc butterfly+epilogue phase. This exact experiment never ran clean:
// R13 was masked by the atomic tail, R16 broke occupancy, R19 only pinned
// within-iteration order (compiler can't hoist loads across the LDS-atomic
// back-edge itself -- R17's VGPR=52 showed it sinks loads to uses instead).
__global__ __launch_bounds__(1024, 4) void loss_main(
    const float* __restrict__ y_pred,
    const int*   __restrict__ y_true,
    double* __restrict__ gLb, unsigned int* __restrict__ gcntb,
    double* __restrict__ gceb, int nrows)
{
    __shared__ float    sL[NCLS];
    __shared__ unsigned scnt[NCLS];
    __shared__ float    sce;

    const int t = threadIdx.x;
    if (t == 0) sce = 0.f;
    if (t < NCLS) { sL[t] = 0.f; scnt[t] = 0u; }
    __syncthreads();

    const int lane = t & 63;
    const int half = lane >> 5;
    const int l32  = lane & 31;
    const int wgl  = blockIdx.x * (blockDim.x >> 6) + (t >> 6);   // 0..4095
    const int nW   = gridDim.x * (blockDim.x >> 6);               // 4096
    const int nPairs = nrows >> 1;
    const int step = nW * 8;

    float ce_local = 0.f;

    float4 v[8]; int lab[8];

    auto LOAD = [&](float4 (&V)[8], int (&L)[8], int pb) {
        const float* base = y_pred + ((size_t)(pb << 1) + half) * NCLS + (l32 << 2);
        #pragma unroll
        for (int u = 0; u < 8; ++u) {
            V[u] = *reinterpret_cast<const float4*>(base + (size_t)(u << 1) * NCLS);
            L[u] = y_true[((pb + u) << 1) + half];
        }
    };

    int p0 = wgl * 8;
    if (p0 + 7 < nPairs) {
        LOAD(v, lab, p0);
        while (true) {
            // ---- EXP phase: v dies here (S, e0, owner-lane tv fold)
            float S[8], e0[8];
            #pragma unroll
            for (int u = 0; u < 8; ++u) {
                const float ex = __expf(v[u].x), ey = __expf(v[u].y);
                const float ez = __expf(v[u].z), ew = __expf(v[u].w);
                e0[u] = ex;                      // valid on lane 0/32 (col 0) only
                S[u]  = (ex + ey) + (ez + ew);
                if ((lab[u] >> 2) == l32) {      // owner lane folds target logit
                    const int ls = lab[u] & 3;
                    ce_local += (ls == 0) ? v[u].x : (ls == 1) ? v[u].y
                              : (ls == 2) ? v[u].z : v[u].w;
                }
            }
            // ---- issue NEXT batch's loads now (v dead); labels double-buffered
            const int  pn = p0 + step;
            const bool hn = (pn + 7 < nPairs);
            int labn[8];
            if (hn) LOAD(v, labn, pn);
            __builtin_amdgcn_sched_barrier(0);   // loads may not sink below here

            // ---- 8 interleaved 5-step butterflies (S lands on all lanes)
            #pragma unroll
            for (int off = 16; off; off >>= 1) {
                #pragma unroll
                for (int u = 0; u < 8; ++u) S[u] += __shfl_xor(S[u], off);
            }
            // ---- distribute: lane l32==u owns row-pair u of its half
            float e0m = 1.f, Sm = 1.f; int labm = 0;
            #pragma unroll
            for (int u = 0; u < 8; ++u) {
                const float b = __shfl(e0[u], half << 5);   // bcast col-0 exp
                if (l32 == u) { e0m = b; Sm = S[u]; labm = lab[u]; }
            }
            // ---- wave-parallel epilogue: 16 lanes (8 per half) at once
            if (l32 < 8) {
                const float logS = __logf(Sm);
                ce_local -= logS;
                const float d = (labm == 0) ? e0m : (Sm - e0m);
                const float c0 = __logf(__fmaf_rn(EPS_, Sm, d)) - logS;
                const float contrib = (labm == 0) ? ALPHA * c0 : c0;
                atomicAdd(&sL[labm], contrib);
                atomicAdd(&scnt[labm], 1u);
            }
            p0 = pn;
            if (!hn) break;
            #pragma unroll
            for (int u = 0; u < 8; ++u) lab[u] = labn[u];
        }
    }
    // tail: leftover single pairs (empty at 262144 rows; kept for generality)
    for (; p0 < nPairs; ++p0) {
        const int row = (p0 << 1) + half;
        const float4 vv = *reinterpret_cast<const float4*>(
            y_pred + (size_t)row * NCLS + (l32 << 2));
        const int lb2 = y_true[row];
        const float ex = __expf(vv.x), ey = __expf(vv.y);
        const float ez = __expf(vv.z), ew = __expf(vv.w);
        float S = (ex + ey) + (ez + ew);
        if ((lb2 >> 2) == l32) {
            const int ls = lb2 & 3;
            ce_local += (ls == 0) ? vv.x : (ls == 1) ? vv.y : (ls == 2) ? vv.z : vv.w;
        }
        #pragma unroll
        for (int off = 16; off; off >>= 1) S += __shfl_xor(S, off);
        if (l32 == 0) {
            const float logS = __logf(S);
            ce_local -= logS;
            const float d = (lb2 == 0) ? ex : (S - ex);
            const float c0 = __logf(__fmaf_rn(EPS_, S, d)) - logS;
            const float contrib = (lb2 == 0) ? ALPHA * c0 : c0;
            atomicAdd(&sL[lb2], contrib);
            atomicAdd(&scnt[lb2], 1u);
        }
    }
    if ((nrows & 1) && wgl == 0) {
        const int row = nrows - 1;
        const float4 vv = *reinterpret_cast<const float4*>(
            y_pred + (size_t)row * NCLS + (l32 << 2));
        const int lb2 = y_true[row];
        if (half == 0) {
            const float ex = __expf(vv.x), ey = __expf(vv.y);
            const float ez = __expf(vv.z), ew = __expf(vv.w);
            float S = (ex + ey) + (ez + ew);
            if ((lb2 >> 2) == l32) {
                const int ls = lb2 & 3;
                ce_local += (ls == 0) ? vv.x : (ls == 1) ? vv.y : (ls == 2) ? vv.z : vv.w;
            }
            #pragma unroll
            for (int off = 16; off; off >>= 1) S += __shfl_xor(S, off);
            if (l32 == 0) {
                const float logS = __logf(S);
                ce_local -= logS;
                const float d = (lb2 == 0) ? ex : (S - ex);
                const float c0 = __logf(__fmaf_rn(EPS_, S, d)) - logS;
                const float contrib = (lb2 == 0) ? ALPHA * c0 : c0;
                atomicAdd(&sL[lb2], contrib);
                atomicAdd(&scnt[lb2], 1u);
            }
        }
    }

    float lp = ce_local;
    #pragma unroll
    for (int off = 32; off; off >>= 1) lp += __shfl_xor(lp, off);
    if (lane == 0) atomicAdd(&sce, lp);
    __syncthreads();

    // coalesced write-flush: block owns row blockIdx.x of [blk][cls] arrays.
    if (t < NCLS) {
        gLb[(size_t)blockIdx.x * NCLS + t]   = (double)sL[t];
        gcntb[(size_t)blockIdx.x * NCLS + t] = scnt[t];
    }
    if (t == 0) gceb[blockIdx.x] = (double)sce;
}

// Parallel finalize: 1024 threads. 8 threads per class x 32 slots, coalesced
// (for fixed slot b, lanes read consecutive classes). LDS tree + wave butterflies.
__global__ __launch_bounds__(1024) void loss_final(
    const double* __restrict__ gLb,          // [256][128]
    const unsigned int* __restrict__ gcntb,  // [256][128]
    const double* __restrict__ gceb,         // [256]
    float* __restrict__ out, int nrows)
{
    __shared__ double sLc[8][NCLS];
    __shared__ double snc[8][NCLS];
    __shared__ double sred[4];

    const int t = threadIdx.x;
    const int c = t & (NCLS - 1);
    const int g = t >> 7;                    // 0..7

    double Lc = 0.0, nc = 0.0;
    for (int b = g * 32; b < g * 32 + 32; ++b) {
        Lc += gLb[(size_t)b * NCLS + c];
        nc += (double)gcntb[(size_t)b * NCLS + c];
    }
    sLc[g][c] = Lc; snc[g][c] = nc;
    __syncthreads();

    if (t < NCLS) {
        double L = 0.0, n = 0.0;
        #pragma unroll
        for (int gg = 0; gg < 8; ++gg) { L += sLc[gg][t]; n += snc[gg][t]; }
        sLc[0][t] = L; snc[0][t] = n;
    }
    __syncthreads();

    const double denom = (double)nrows - snc[0][0];
    double local = 0.0;
    if (t < NCLS) {
        const double L = sLc[0][t], n = snc[0][t];
        local = (t == 0) ? L : (double)BETA_ * (1.0 - n / denom) * L;
    }
    #pragma unroll
    for (int off = 32; off; off >>= 1) local += __shfl_xor(local, off);
    if (t < NCLS && (t & 63) == 0) sred[t >> 6] = local;   // sred[0], sred[1]

    if (t >= 128 && t < 192) {               // one wave sums gceb[256]
        const int l = t - 128;
        double cep = gceb[l] + gceb[l + 64] + gceb[l + 128] + gceb[l + 192];
        #pragma unroll
        for (int off = 32; off; off >>= 1) cep += __shfl_xor(cep, off);
        if (l == 0) sred[2] = cep;
    }
    __syncthreads();

    if (t == 0) {
        const double ce = -sred[2] / (double)nrows;
        out[0] = (float)(ce - (sred[0] + sred[1]) / (double)nrows);
    }
}

extern "C" void kernel_launch(void* const* d_in, const int* in_sizes, int n_in,
                              void* d_out, int out_size, void* d_ws, size_t ws_size,
                              hipStream_t stream) {
    const float* y_pred = (const float*)d_in[0];
    const int*   y_true = (const int*)d_in[1];
    const int nrows = in_sizes[1];

    double*   gLb   = (double*)d_ws;                          // 262144 B
    double*   gceb  = (double*)((char*)d_ws + 262144);        // 2048 B
    unsigned* gcntb = (unsigned*)((char*)d_ws + 264192);      // 131072 B

    loss_main<<<dim3(NBLK), dim3(1024), 0, stream>>>(y_pred, y_true, gLb, gcntb, gceb, nrows);
    loss_final<<<dim3(1), dim3(1024), 0, stream>>>(gLb, gcntb, gceb, (float*)d_out, nrows);
}

// Round 30
// 35.742 us; speedup vs baseline: 2.5846x; 1.0375x over previous
//
#include <hip/hip_runtime.h>
#include <math.h>
#include <stdint.h>

#define NCLS 128
#define NBLK 256
constexpr float ALPHA = 0.5f;
constexpr float BETA_ = 0.5f;
constexpr float EPS_ = 1e-9f;

// ws: gLb[256][128] double | gceb[256] double | gcntb[256][128] uint (atomic-free
// coalesced flush; every slot stored every launch -> no zeroing kernel).

// R29 (rotated pipeline) + MERGE-TREE REDUCTION: the 8-value cross-lane sum now
// sends half the live values at each xor step (4+2+1+1+1 = 9 shuffles for all
// 16 rows) instead of 8 full butterflies (40 shuffles). DS-pipe issue per batch
// drops 48 -> 17 ops; DS was the one pipe never attacked (est. ~7.4us/CU serial).
// Row-pair u lands on 4-lane group (l32>>2)==u; owners (l32&3)==0 keep the
// 16-lane-parallel epilogue.
__global__ __launch_bounds__(1024, 4) void loss_main(
    const float* __restrict__ y_pred,
    const int*   __restrict__ y_true,
    double* __restrict__ gLb, unsigned int* __restrict__ gcntb,
    double* __restrict__ gceb, int nrows)
{
    __shared__ float    sL[NCLS];
    __shared__ unsigned scnt[NCLS];
    __shared__ float    sce;

    const int t = threadIdx.x;
    if (t == 0) sce = 0.f;
    if (t < NCLS) { sL[t] = 0.f; scnt[t] = 0u; }
    __syncthreads();

    const int lane = t & 63;
    const int half = lane >> 5;
    const int l32  = lane & 31;
    const int wgl  = blockIdx.x * (blockDim.x >> 6) + (t >> 6);   // 0..4095
    const int nW   = gridDim.x * (blockDim.x >> 6);               // 4096
    const int nPairs = nrows >> 1;
    const int step = nW * 8;

    const bool hi16 = (l32 & 16) != 0;
    const bool hi8  = (l32 & 8)  != 0;
    const bool hi4  = (l32 & 4)  != 0;
    const int  uown = (l32 >> 2) & 7;          // row-pair owned by this 4-lane group
    const bool isowner = (l32 & 3) == 0;

    float ce_local = 0.f;

    float4 v[8]; int lab[8];

    auto LOAD = [&](float4 (&V)[8], int (&L)[8], int pb) {
        const float* base = y_pred + ((size_t)(pb << 1) + half) * NCLS + (l32 << 2);
        #pragma unroll
        for (int u = 0; u < 8; ++u) {
            V[u] = *reinterpret_cast<const float4*>(base + (size_t)(u << 1) * NCLS);
            L[u] = y_true[((pb + u) << 1) + half];
        }
    };

    int p0 = wgl * 8;
    if (p0 + 7 < nPairs) {
        LOAD(v, lab, p0);
        while (true) {
            // ---- EXP phase: v dies here (S, e0, owner-lane tv fold)
            float S[8], e0[8];
            #pragma unroll
            for (int u = 0; u < 8; ++u) {
                const float ex = __expf(v[u].x), ey = __expf(v[u].y);
                const float ez = __expf(v[u].z), ew = __expf(v[u].w);
                e0[u] = ex;                      // valid on lane 0/32 (col 0) only
                S[u]  = (ex + ey) + (ez + ew);
                if ((lab[u] >> 2) == l32) {      // owner lane folds target logit
                    const int ls = lab[u] & 3;
                    ce_local += (ls == 0) ? v[u].x : (ls == 1) ? v[u].y
                              : (ls == 2) ? v[u].z : v[u].w;
                }
            }
            // ---- issue NEXT batch's loads now (v dead); labels double-buffered
            const int  pn = p0 + step;
            const bool hn = (pn + 7 < nPairs);
            int labn[8];
            if (hn) LOAD(v, labn, pn);
            __builtin_amdgcn_sched_barrier(0);   // loads may not sink below here

            // ---- merge-tree reduce: 9 shuffles total for all 8 row-pairs/half
            // xor16: keep 4, send 4
            float A0, A1, A2, A3;
            {
                const float s0 = hi16 ? S[0] : S[4];
                const float s1 = hi16 ? S[1] : S[5];
                const float s2 = hi16 ? S[2] : S[6];
                const float s3 = hi16 ? S[3] : S[7];
                A0 = (hi16 ? S[4] : S[0]) + __shfl_xor(s0, 16);
                A1 = (hi16 ? S[5] : S[1]) + __shfl_xor(s1, 16);
                A2 = (hi16 ? S[6] : S[2]) + __shfl_xor(s2, 16);
                A3 = (hi16 ? S[7] : S[3]) + __shfl_xor(s3, 16);
            }
            // xor8: keep 2, send 2
            float B0, B1;
            {
                const float s0 = hi8 ? A0 : A2;
                const float s1 = hi8 ? A1 : A3;
                B0 = (hi8 ? A2 : A0) + __shfl_xor(s0, 8);
                B1 = (hi8 ? A3 : A1) + __shfl_xor(s1, 8);
            }
            // xor4: keep 1, send 1
            float C0;
            {
                const float s = hi4 ? B0 : B1;
                C0 = (hi4 ? B1 : B0) + __shfl_xor(s, 4);
            }
            // finish within the 4-lane owner group
            C0 += __shfl_xor(C0, 2);
            C0 += __shfl_xor(C0, 1);             // C0 = S_total for row-pair uown

            // ---- e0 broadcast to owner groups (8 shuffles, select-style)
            float e0m = 1.f;
            #pragma unroll
            for (int u = 0; u < 8; ++u) {
                const float b = __shfl(e0[u], half << 5);
                if (uown == u) e0m = b;
            }
            int labm = 0;
            #pragma unroll
            for (int u = 0; u < 8; ++u) if (uown == u) labm = lab[u];

            // ---- wave-parallel epilogue: 16 owner lanes (8 per half)
            if (isowner) {
                const float Sm = C0;
                const float logS = __logf(Sm);
                ce_local -= logS;
                const float d = (labm == 0) ? e0m : (Sm - e0m);
                const float c0 = __logf(__fmaf_rn(EPS_, Sm, d)) - logS;
                const float contrib = (labm == 0) ? ALPHA * c0 : c0;
                atomicAdd(&sL[labm], contrib);
                atomicAdd(&scnt[labm], 1u);
            }
            p0 = pn;
            if (!hn) break;
            #pragma unroll
            for (int u = 0; u < 8; ++u) lab[u] = labn[u];
        }
    }
    // tail: leftover single pairs (empty at 262144 rows; kept for generality)
    for (; p0 < nPairs; ++p0) {
        const int row = (p0 << 1) + half;
        const float4 vv = *reinterpret_cast<const float4*>(
            y_pred + (size_t)row * NCLS + (l32 << 2));
        const int lb2 = y_true[row];
        const float ex = __expf(vv.x), ey = __expf(vv.y);
        const float ez = __expf(vv.z), ew = __expf(vv.w);
        float S = (ex + ey) + (ez + ew);
        if ((lb2 >> 2) == l32) {
            const int ls = lb2 & 3;
            ce_local += (ls == 0) ? vv.x : (ls == 1) ? vv.y : (ls == 2) ? vv.z : vv.w;
        }
        #pragma unroll
        for (int off = 16; off; off >>= 1) S += __shfl_xor(S, off);
        if (l32 == 0) {
            const float logS = __logf(S);
            ce_local -= logS;
            const float d = (lb2 == 0) ? ex : (S - ex);
            const float c0 = __logf(__fmaf_rn(EPS_, S, d)) - logS;
            const float contrib = (lb2 == 0) ? ALPHA * c0 : c0;
            atomicAdd(&sL[lb2], contrib);
            atomicAdd(&scnt[lb2], 1u);
        }
    }
    if ((nrows & 1) && wgl == 0) {
        const int row = nrows - 1;
        const float4 vv = *reinterpret_cast<const float4*>(
            y_pred + (size_t)row * NCLS + (l32 << 2));
        const int lb2 = y_true[row];
        if (half == 0) {
            const float ex = __expf(vv.x), ey = __expf(vv.y);
            const float ez = __expf(vv.z), ew = __expf(vv.w);
            float S = (ex + ey) + (ez + ew);
            if ((lb2 >> 2) == l32) {
                const int ls = lb2 & 3;
                ce_local += (ls == 0) ? vv.x : (ls == 1) ? vv.y : (ls == 2) ? vv.z : vv.w;
            }
            #pragma unroll
            for (int off = 16; off; off >>= 1) S += __shfl_xor(S, off);
            if (l32 == 0) {
                const float logS = __logf(S);
                ce_local -= logS;
                const float d = (lb2 == 0) ? ex : (S - ex);
                const float c0 = __logf(__fmaf_rn(EPS_, S, d)) - logS;
                const float contrib = (lb2 == 0) ? ALPHA * c0 : c0;
                atomicAdd(&sL[lb2], contrib);
                atomicAdd(&scnt[lb2], 1u);
            }
        }
    }

    float lp = ce_local;
    #pragma unroll
    for (int off = 32; off; off >>= 1) lp += __shfl_xor(lp, off);
    if (lane == 0) atomicAdd(&sce, lp);
    __syncthreads();

    // coalesced write-flush: block owns row blockIdx.x of [blk][cls] arrays.
    if (t < NCLS) {
        gLb[(size_t)blockIdx.x * NCLS + t]   = (double)sL[t];
        gcntb[(size_t)blockIdx.x * NCLS + t] = scnt[t];
    }
    if (t == 0) gceb[blockIdx.x] = (double)sce;
}

// Parallel finalize: 1024 threads. 8 threads per class x 32 slots, coalesced
// (for fixed slot b, lanes read consecutive classes). LDS tree + wave butterflies.
__global__ __launch_bounds__(1024) void loss_final(
    const double* __restrict__ gLb,          // [256][128]
    const unsigned int* __restrict__ gcntb,  // [256][128]
    const double* __restrict__ gceb,         // [256]
    float* __restrict__ out, int nrows)
{
    __shared__ double sLc[8][NCLS];
    __shared__ double snc[8][NCLS];
    __shared__ double sred[4];

    const int t = threadIdx.x;
    const int c = t & (NCLS - 1);
    const int g = t >> 7;                    // 0..7

    double Lc = 0.0, nc = 0.0;
    for (int b = g * 32; b < g * 32 + 32; ++b) {
        Lc += gLb[(size_t)b * NCLS + c];
        nc += (double)gcntb[(size_t)b * NCLS + c];
    }
    sLc[g][c] = Lc; snc[g][c] = nc;
    __syncthreads();

    if (t < NCLS) {
        double L = 0.0, n = 0.0;
        #pragma unroll
        for (int gg = 0; gg < 8; ++gg) { L += sLc[gg][t]; n += snc[gg][t]; }
        sLc[0][t] = L; snc[0][t] = n;
    }
    __syncthreads();

    const double denom = (double)nrows - snc[0][0];
    double local = 0.0;
    if (t < NCLS) {
        const double L = sLc[0][t], n = snc[0][t];
        local = (t == 0) ? L : (double)BETA_ * (1.0 - n / denom) * L;
    }
    #pragma unroll
    for (int off = 32; off; off >>= 1) local += __shfl_xor(local, off);
    if (t < NCLS && (t & 63) == 0) sred[t >> 6] = local;   // sred[0], sred[1]

    if (t >= 128 && t < 192) {               // one wave sums gceb[256]
        const int l = t - 128;
        double cep = gceb[l] + gceb[l + 64] + gceb[l + 128] + gceb[l + 192];
        #pragma unroll
        for (int off = 32; off; off >>= 1) cep += __shfl_xor(cep, off);
        if (l == 0) sred[2] = cep;
    }
    __syncthreads();

    if (t == 0) {
        const double ce = -sred[2] / (double)nrows;
        out[0] = (float)(ce - (sred[0] + sred[1]) / (double)nrows);
    }
}

extern "C" void kernel_launch(void* const* d_in, const int* in_sizes, int n_in,
                              void* d_out, int out_size, void* d_ws, size_t ws_size,
                              hipStream_t stream) {
    const float* y_pred = (const float*)d_in[0];
    const int*   y_true = (const int*)d_in[1];
    const int nrows = in_sizes[1];

    double*   gLb   = (double*)d_ws;                          // 262144 B
    double*   gceb  = (double*)((char*)d_ws + 262144);        // 2048 B
    unsigned* gcntb = (unsigned*)((char*)d_ws + 264192);      // 131072 B

    loss_main<<<dim3(NBLK), dim3(1024), 0, stream>>>(y_pred, y_true, gLb, gcntb, gceb, nrows);
    loss_final<<<dim3(1), dim3(1024), 0, stream>>>(gLb, gcntb, gceb, (float*)d_out, nrows);
}